// Round 2
// baseline (13492.693 us; speedup 1.0000x reference)
//
#include <hip/hip_runtime.h>

typedef __bf16 bf16x8 __attribute__((ext_vector_type(8)));
typedef float f32x4 __attribute__((ext_vector_type(4)));

static constexpr int B = 32, T = 512, IN = 2048, H = 512;
static constexpr int G4 = 4 * H;      // 2048 gate columns
static constexpr int M_ALL = B * T;   // 16384
static constexpr int NWG = 16;        // workgroups in scan (all co-resident)

// ---------- helpers ----------
__device__ __forceinline__ ushort f2b(float f) {  // fp32 -> bf16 RNE
  unsigned u = __float_as_uint(f);
  u = (u + 0x7FFFu + ((u >> 16) & 1u)) >> 16;
  return (ushort)u;
}
__device__ __forceinline__ float b2f(ushort h) {
  return __uint_as_float(((unsigned)h) << 16);
}
__device__ __forceinline__ float fast_sigmoid(float x) {
  float e = __expf(-x);
  return 1.0f / (1.0f + e);
}
__device__ __forceinline__ float fast_tanh(float x) {
  float ax = fabsf(x);
  float e = __expf(-2.0f * ax);
  float t = (1.0f - e) / (1.0f + e);
  return copysignf(t, x);
}
// split 8 fp32 into bf16 hi + bf16 lo (residual), packed as uint4 each
__device__ __forceinline__ void split8(const float4 a, const float4 b, uint4& hi, uint4& lo) {
  float x[8] = {a.x, a.y, a.z, a.w, b.x, b.y, b.z, b.w};
  ushort h[8], l[8];
#pragma unroll
  for (int i = 0; i < 8; ++i) {
    h[i] = f2b(x[i]);
    l[i] = f2b(x[i] - b2f(h[i]));
  }
  hi = make_uint4(h[0] | ((unsigned)h[1] << 16), h[2] | ((unsigned)h[3] << 16),
                  h[4] | ((unsigned)h[5] << 16), h[6] | ((unsigned)h[7] << 16));
  lo = make_uint4(l[0] | ((unsigned)l[1] << 16), l[2] | ((unsigned)l[3] << 16),
                  l[4] | ((unsigned)l[5] << 16), l[6] | ((unsigned)l[7] << 16));
}

// ---------- C[M,N] = A[M,K]*Bm[N,K]^T + bias1[N]+bias2[N], split-bf16 (3-term) ----------
// AF32: A is fp32 (split during staging). Else A is pre-split bf16 planes Ahi/Alo.
// B (weights) always fp32, split during staging. fp32-accurate result.
template <bool AF32>
__global__ __launch_bounds__(256) void gemm3(
    const float* __restrict__ Af,
    const ushort* __restrict__ Ahi, const ushort* __restrict__ Alo,
    const float* __restrict__ Bf,
    const float* __restrict__ bias1, const float* __restrict__ bias2,
    float* __restrict__ C, int M, int N, int K) {
  __shared__ ushort AsH[128][40], AsL[128][40], BsH[128][40], BsL[128][40];
  const int m0 = blockIdx.x * 128, n0 = blockIdx.y * 128;
  const int tid = threadIdx.x, lane = tid & 63, wave = tid >> 6;
  const int wm = (wave & 1) * 64, wn = (wave >> 1) * 64;
  const int lrow = lane & 15, lq = lane >> 4;
  const int sr = tid >> 2;        // staging row 0..63
  const int sk = (tid & 3) * 8;   // staging k offset (elements)

  f32x4 acc[4][4] = {};

  for (int k0 = 0; k0 < K; k0 += 32) {
    __syncthreads();
#pragma unroll
    for (int half = 0; half < 2; ++half) {
      const int r = sr + half * 64;
      uint4 hi, lo;
      if constexpr (AF32) {
        const float* p = Af + (long)(m0 + r) * K + k0 + sk;
        split8(*(const float4*)p, *(const float4*)(p + 4), hi, lo);
      } else {
        hi = *(const uint4*)(Ahi + (long)(m0 + r) * K + k0 + sk);
        lo = *(const uint4*)(Alo + (long)(m0 + r) * K + k0 + sk);
      }
      *(uint4*)&AsH[r][sk] = hi;
      *(uint4*)&AsL[r][sk] = lo;
      const float* q = Bf + (long)(n0 + r) * K + k0 + sk;
      uint4 bh, bl;
      split8(*(const float4*)q, *(const float4*)(q + 4), bh, bl);
      *(uint4*)&BsH[r][sk] = bh;
      *(uint4*)&BsL[r][sk] = bl;
    }
    __syncthreads();
    bf16x8 aH[4], aL[4], bH[4], bL[4];
#pragma unroll
    for (int i = 0; i < 4; ++i) {
      aH[i] = __builtin_bit_cast(bf16x8, *(const uint4*)&AsH[wm + i * 16 + lrow][lq * 8]);
      aL[i] = __builtin_bit_cast(bf16x8, *(const uint4*)&AsL[wm + i * 16 + lrow][lq * 8]);
      bH[i] = __builtin_bit_cast(bf16x8, *(const uint4*)&BsH[wn + i * 16 + lrow][lq * 8]);
      bL[i] = __builtin_bit_cast(bf16x8, *(const uint4*)&BsL[wn + i * 16 + lrow][lq * 8]);
    }
#pragma unroll
    for (int mt = 0; mt < 4; ++mt)
#pragma unroll
      for (int nt = 0; nt < 4; ++nt) {
        acc[mt][nt] = __builtin_amdgcn_mfma_f32_16x16x32_bf16(aH[mt], bH[nt], acc[mt][nt], 0, 0, 0);
        acc[mt][nt] = __builtin_amdgcn_mfma_f32_16x16x32_bf16(aH[mt], bL[nt], acc[mt][nt], 0, 0, 0);
        acc[mt][nt] = __builtin_amdgcn_mfma_f32_16x16x32_bf16(aL[mt], bH[nt], acc[mt][nt], 0, 0, 0);
      }
  }

#pragma unroll
  for (int mt = 0; mt < 4; ++mt)
#pragma unroll
    for (int nt = 0; nt < 4; ++nt) {
      const int col = n0 + wn + nt * 16 + lrow;
      const float bsum = bias1[col] + bias2[col];
#pragma unroll
      for (int r = 0; r < 4; ++r) {
        const int row = m0 + wm + mt * 16 + lq * 4 + r;
        C[(long)row * N + col] = acc[mt][nt][r] + bsum;
      }
    }
}

// ---------- recurrent scan: regular launch, custom device-scope barrier ----------
// 16 WGs x 256 = 64 waves. Wave gw: j-tile (gw>>1)*16, batch half (gw&1)*16.
// W_hh bf16 fragments pinned in registers (4 gates x 16 ktiles x 4 VGPR = 256).
// h carried as bf16 hi+lo planes (2x MFMA) for ~fp32 recurrent precision.
// Per-step barrier: __threadfence (wbl2/inv across XCD L2s) + per-t counter.
__global__ __launch_bounds__(256, 1) void lstm_scan(
    const float* __restrict__ Whh,    // [2048][512] fp32
    const float* __restrict__ xg,     // [B*T][2048] fp32, row m=b*T+t
    ushort* __restrict__ seq_hi,      // [B*T][512] bf16-hi (layer0) or null
    ushort* __restrict__ seq_lo,      // [B*T][512] bf16-lo (layer0) or null
    float* __restrict__ seq_f32,      // [B*T][512] fp32 (layer1) or null
    ushort* __restrict__ hbuf,        // [2 slots][2 planes][B][H] ushort
    unsigned* __restrict__ cnt) {     // [T] zeroed counters
  const int tid = threadIdx.x, lane = tid & 63;
  const int gw = blockIdx.x * 4 + (tid >> 6);
  const int j0 = (gw >> 1) * 16, b0 = (gw & 1) * 16;
  const int lrow = lane & 15, lq = lane >> 4;

  // Load W_hh fragments (bf16, B-operand layout: n=lane&15 -> Whh row, k -> col)
  bf16x8 Wf[4][16];
#pragma unroll
  for (int q = 0; q < 4; ++q)
#pragma unroll
    for (int kt = 0; kt < 16; ++kt) {
      const float* p = Whh + (long)(q * 512 + j0 + lrow) * 512 + kt * 32 + lq * 8;
      float4 w0 = *(const float4*)p, w1 = *(const float4*)(p + 4);
      uint4 hi, lo;
      split8(w0, w1, hi, lo);
      Wf[q][kt] = __builtin_bit_cast(bf16x8, hi);
    }

  float c[4] = {0.f, 0.f, 0.f, 0.f};

  for (int t = 0; t < T; ++t) {
    // prefetch xg (issues early; latency overlaps the h-MFMA loop below)
    float xgv[4][4];
#pragma unroll
    for (int q = 0; q < 4; ++q)
#pragma unroll
      for (int r = 0; r < 4; ++r)
        xgv[q][r] = xg[((long)(b0 + lq * 4 + r) * T + t) * G4 + q * 512 + j0 + lrow];

    f32x4 acc[4] = {};
    if (t > 0) {
      const ushort* hp = hbuf + (size_t)(t & 1) * 2 * B * H;  // slot base
#pragma unroll
      for (int kt = 0; kt < 16; ++kt) {
        bf16x8 ah = __builtin_bit_cast(bf16x8, *(const uint4*)(hp + (b0 + lrow) * H + kt * 32 + lq * 8));
        bf16x8 al = __builtin_bit_cast(bf16x8, *(const uint4*)(hp + B * H + (b0 + lrow) * H + kt * 32 + lq * 8));
#pragma unroll
        for (int q = 0; q < 4; ++q)
          acc[q] = __builtin_amdgcn_mfma_f32_16x16x32_bf16(ah, Wf[q][kt], acc[q], 0, 0, 0);
#pragma unroll
        for (int q = 0; q < 4; ++q)
          acc[q] = __builtin_amdgcn_mfma_f32_16x16x32_bf16(al, Wf[q][kt], acc[q], 0, 0, 0);
      }
    }

    ushort* hn = hbuf + (size_t)((t + 1) & 1) * 2 * B * H;
#pragma unroll
    for (int r = 0; r < 4; ++r) {
      const float pi = acc[0][r] + xgv[0][r];
      const float pf = acc[1][r] + xgv[1][r];
      const float pg = acc[2][r] + xgv[2][r];
      const float po = acc[3][r] + xgv[3][r];
      const float iv = fast_sigmoid(pi);
      const float fv = fast_sigmoid(pf);
      const float gv = fast_tanh(pg);
      const float ov = fast_sigmoid(po);
      c[r] = fv * c[r] + iv * gv;
      const float h = ov * fast_tanh(c[r]);
      const int b = b0 + lq * 4 + r, j = j0 + lrow;
      const ushort hi = f2b(h);
      const ushort lo = f2b(h - b2f(hi));
      hn[b * H + j] = hi;
      hn[B * H + b * H + j] = lo;
      if (seq_hi) {
        const long o = ((long)b * T + t) * H + j;
        seq_hi[o] = hi;
        seq_lo[o] = lo;
      }
      if (seq_f32) seq_f32[((long)b * T + t) * H + j] = h;
    }

    // ---- device-scope barrier (no cooperative API) ----
    __threadfence();   // release: flush h stores past this XCD's L2
    __syncthreads();
    if (tid == 0) {
      __hip_atomic_fetch_add(&cnt[t], 1u, __ATOMIC_RELAXED, __HIP_MEMORY_SCOPE_AGENT);
      while (__hip_atomic_load(&cnt[t], __ATOMIC_RELAXED, __HIP_MEMORY_SCOPE_AGENT) < (unsigned)NWG)
        __builtin_amdgcn_s_sleep(1);
    }
    __syncthreads();
    __threadfence();   // acquire: invalidate L1/L2 so next-step h loads are fresh
  }
}

// ---------- launch ----------
extern "C" void kernel_launch(void* const* d_in, const int* in_sizes, int n_in,
                              void* d_out, int out_size, void* d_ws, size_t ws_size,
                              hipStream_t stream) {
  const float* feats = (const float*)d_in[0];
  const float* Wih0 = (const float*)d_in[1];
  const float* Whh0 = (const float*)d_in[2];
  const float* bih0 = (const float*)d_in[3];
  const float* bhh0 = (const float*)d_in[4];
  const float* Wih1 = (const float*)d_in[5];
  const float* Whh1 = (const float*)d_in[6];
  const float* bih1 = (const float*)d_in[7];
  const float* bhh1 = (const float*)d_in[8];

  // workspace layout (bytes), hand-checked:
  //   xg      : [0, 134217728)                 16384*2048*4
  //   seq_hi  : [134217728, 150994944)         16384*512*2
  //   seq_lo  : [150994944, 167772160)         16384*512*2
  //   hbuf    : [167772160, 167903232)         2*2*32*512*2
  //   cnt     : [167903232, 167907328)         2*512*4
  char* ws = (char*)d_ws;
  float* xg       = (float*)(ws + 0);
  ushort* seq_hi  = (ushort*)(ws + 134217728);
  ushort* seq_lo  = (ushort*)(ws + 150994944);
  ushort* hbuf    = (ushort*)(ws + 167772160);
  unsigned* cnt   = (unsigned*)(ws + 167903232);

  // zero the barrier counters (ws is re-poisoned before every call)
  hipMemsetAsync(cnt, 0, 2 * T * sizeof(unsigned), stream);

  // layer 0 input GEMM: xg = feats * Wih0^T + (bih0 + bhh0)   [fp32-accurate]
  gemm3<true><<<dim3(M_ALL / 128, G4 / 128), dim3(256), 0, stream>>>(
      feats, nullptr, nullptr, Wih0, bih0, bhh0, xg, M_ALL, G4, IN);

  // layer 0 scan -> seq_hi/seq_lo
  lstm_scan<<<dim3(NWG), dim3(256), 0, stream>>>(
      Whh0, xg, seq_hi, seq_lo, nullptr, hbuf, cnt);

  // layer 1 input GEMM: xg = h1 * Wih1^T + (bih1 + bhh1)
  gemm3<false><<<dim3(M_ALL / 128, G4 / 128), dim3(256), 0, stream>>>(
      nullptr, seq_hi, seq_lo, Wih1, bih1, bhh1, xg, M_ALL, G4, H);

  // layer 1 scan -> d_out (fp32)
  lstm_scan<<<dim3(NWG), dim3(256), 0, stream>>>(
      Whh1, xg, nullptr, nullptr, (float*)d_out, hbuf, cnt + T);
}

// Round 5
// 7915.732 us; speedup vs baseline: 1.7045x; 1.7045x over previous
//
#include <hip/hip_runtime.h>

typedef __bf16 bf16x8 __attribute__((ext_vector_type(8)));
typedef float f32x4 __attribute__((ext_vector_type(4)));

static constexpr int B = 32, T = 512, IN = 2048, H = 512;
static constexpr int G4 = 4 * H;      // 2048 gate columns
static constexpr int M_ALL = B * T;   // 16384
static constexpr int NWG = 16;        // scan workgroups (8 per batch-half)
static constexpr unsigned NHALF = 8;  // barrier arrivals per half

// ---------- helpers ----------
__device__ __forceinline__ ushort f2b(float f) {  // fp32 -> bf16 RNE
  unsigned u = __float_as_uint(f);
  u = (u + 0x7FFFu + ((u >> 16) & 1u)) >> 16;
  return (ushort)u;
}
__device__ __forceinline__ float b2f(ushort h) {
  return __uint_as_float(((unsigned)h) << 16);
}
__device__ __forceinline__ float fast_sigmoid(float x) {
  float e = __expf(-x);
  return 1.0f / (1.0f + e);
}
__device__ __forceinline__ float fast_tanh(float x) {
  float ax = fabsf(x);
  float e = __expf(-2.0f * ax);
  float t = (1.0f - e) / (1.0f + e);
  return copysignf(t, x);
}
// split 8 fp32 into bf16 hi + bf16 lo (residual), packed as uint4 each
__device__ __forceinline__ void split8(const float4 a, const float4 b, uint4& hi, uint4& lo) {
  float x[8] = {a.x, a.y, a.z, a.w, b.x, b.y, b.z, b.w};
  ushort h[8], l[8];
#pragma unroll
  for (int i = 0; i < 8; ++i) {
    h[i] = f2b(x[i]);
    l[i] = f2b(x[i] - b2f(h[i]));
  }
  hi = make_uint4(h[0] | ((unsigned)h[1] << 16), h[2] | ((unsigned)h[3] << 16),
                  h[4] | ((unsigned)h[5] << 16), h[6] | ((unsigned)h[7] << 16));
  lo = make_uint4(l[0] | ((unsigned)l[1] << 16), l[2] | ((unsigned)l[3] << 16),
                  l[4] | ((unsigned)l[5] << 16), l[6] | ((unsigned)l[7] << 16));
}
__device__ __forceinline__ bf16x8 f2b8(const float* p) {  // 8 fp32 -> bf16x8 (hi)
  float4 a = *(const float4*)p, b = *(const float4*)(p + 4);
  uint4 u;
  u.x = f2b(a.x) | ((unsigned)f2b(a.y) << 16);
  u.y = f2b(a.z) | ((unsigned)f2b(a.w) << 16);
  u.z = f2b(b.x) | ((unsigned)f2b(b.y) << 16);
  u.w = f2b(b.z) | ((unsigned)f2b(b.w) << 16);
  return __builtin_bit_cast(bf16x8, u);
}

// ---------- coherent (agent-scope) producer store ----------
// asm volatile + "memory": real memory ops (atomics, plain stores) cannot be
// reordered across it; mutual order of volatile asms is preserved.
__device__ __forceinline__ void st_coh_u16(void* p, ushort v) {
  unsigned vv = v;
  asm volatile("global_store_short %0, %1, off sc1" :: "v"(p), "v"(vv) : "memory");
}
__device__ __forceinline__ void wait_vm0() {
  asm volatile("s_waitcnt vmcnt(0)" ::: "memory");
}

// ---------- GEMM: C[M,N] = A[M,K]*Bm[N,K]^T + bias1[N]+bias2[N] ----------
// AMODE 0: A fp32, split hi/lo during staging (3-term, fp32-accurate).
// AMODE 2: A bf16 (2-term: aH*bH + aH*bL). B (weights) fp32, split on stage.
template <int AMODE>
__global__ __launch_bounds__(256) void gemm3(
    const float* __restrict__ Af, const ushort* __restrict__ Abf,
    const float* __restrict__ Bf,
    const float* __restrict__ bias1, const float* __restrict__ bias2,
    float* __restrict__ C, int M, int N, int K) {
  __shared__ ushort AsH[128][40], AsL[128][40], BsH[128][40], BsL[128][40];
  const int m0 = blockIdx.x * 128, n0 = blockIdx.y * 128;
  const int tid = threadIdx.x, lane = tid & 63, wave = tid >> 6;
  const int wm = (wave & 1) * 64, wn = (wave >> 1) * 64;
  const int lrow = lane & 15, lq = lane >> 4;
  const int sr = tid >> 2;        // staging row 0..63
  const int sk = (tid & 3) * 8;   // staging k offset (elements)

  f32x4 acc[4][4] = {};

  for (int k0 = 0; k0 < K; k0 += 32) {
    __syncthreads();
#pragma unroll
    for (int half = 0; half < 2; ++half) {
      const int r = sr + half * 64;
      if constexpr (AMODE == 0) {
        const float* p = Af + (long)(m0 + r) * K + k0 + sk;
        uint4 hi, lo;
        split8(*(const float4*)p, *(const float4*)(p + 4), hi, lo);
        *(uint4*)&AsH[r][sk] = hi;
        *(uint4*)&AsL[r][sk] = lo;
      } else {
        *(uint4*)&AsH[r][sk] = *(const uint4*)(Abf + (long)(m0 + r) * K + k0 + sk);
      }
      const float* q = Bf + (long)(n0 + r) * K + k0 + sk;
      uint4 bh, bl;
      split8(*(const float4*)q, *(const float4*)(q + 4), bh, bl);
      *(uint4*)&BsH[r][sk] = bh;
      *(uint4*)&BsL[r][sk] = bl;
    }
    __syncthreads();
    bf16x8 aH[4], aL[4], bH[4], bL[4];
#pragma unroll
    for (int i = 0; i < 4; ++i) {
      aH[i] = __builtin_bit_cast(bf16x8, *(const uint4*)&AsH[wm + i * 16 + lrow][lq * 8]);
      if constexpr (AMODE == 0)
        aL[i] = __builtin_bit_cast(bf16x8, *(const uint4*)&AsL[wm + i * 16 + lrow][lq * 8]);
      bH[i] = __builtin_bit_cast(bf16x8, *(const uint4*)&BsH[wn + i * 16 + lrow][lq * 8]);
      bL[i] = __builtin_bit_cast(bf16x8, *(const uint4*)&BsL[wn + i * 16 + lrow][lq * 8]);
    }
#pragma unroll
    for (int mt = 0; mt < 4; ++mt)
#pragma unroll
      for (int nt = 0; nt < 4; ++nt) {
        acc[mt][nt] = __builtin_amdgcn_mfma_f32_16x16x32_bf16(aH[mt], bH[nt], acc[mt][nt], 0, 0, 0);
        acc[mt][nt] = __builtin_amdgcn_mfma_f32_16x16x32_bf16(aH[mt], bL[nt], acc[mt][nt], 0, 0, 0);
        if constexpr (AMODE == 0)
          acc[mt][nt] = __builtin_amdgcn_mfma_f32_16x16x32_bf16(aL[mt], bH[nt], acc[mt][nt], 0, 0, 0);
      }
  }

#pragma unroll
  for (int mt = 0; mt < 4; ++mt)
#pragma unroll
    for (int nt = 0; nt < 4; ++nt) {
      const int col = n0 + wn + nt * 16 + lrow;
      const float bsum = bias1[col] + bias2[col];
#pragma unroll
      for (int r = 0; r < 4; ++r) {
        const int row = m0 + wm + mt * 16 + lq * 4 + r;
        C[(long)row * N + col] = acc[mt][nt][r] + bsum;
      }
    }
}

// ---------- recurrent scan ----------
// 16 WGs x 256 thr. blockIdx>>3 = batch half (independent recurrence, own
// barrier group of 8 WGs). Within half: j-tile = (blockIdx&7)*4 + wave.
// W_hh bf16 fragments pinned in registers. h carried bf16.
// h exchange at agent scope (sc1, IF$-coherent): producer = asm sc1 stores +
// vmcnt(0) + counter fetch_add; consumer = COMPILER-VISIBLE 64-bit relaxed
// atomic loads (backend emits sc1 loads AND tracks vmcnt -> no use-before-
// wait hazard, which is what NaN'd round 4's raw-asm loads).
__global__ __launch_bounds__(256, 1) void lstm_scan(
    const float* __restrict__ Whh,    // [2048][512] fp32
    const float* __restrict__ xg,     // [B*T][2048] fp32, row m=b*T+t
    ushort* __restrict__ seq_bf,      // [B*T][512] bf16 (layer0) or null
    float* __restrict__ seq_f32,      // [B*T][512] fp32 (layer1) or null
    ushort* __restrict__ hbuf,        // [2 slots][B][H] ushort, coherent
    unsigned* __restrict__ cnt) {     // [2][T] zeroed counters (per half)
  const int tid = threadIdx.x, lane = tid & 63;
  const int half = blockIdx.x >> 3;
  const int j0 = ((blockIdx.x & 7) * 4 + (tid >> 6)) * 16;
  const int b0 = half * 16;
  const int lrow = lane & 15, lq = lane >> 4;
  unsigned* mycnt = cnt + half * T;

  // W_hh -> registers (bf16 hi). B-operand layout: n=lane&15 -> Whh row.
  bf16x8 Wf[4][16];
#pragma unroll
  for (int q = 0; q < 4; ++q)
#pragma unroll
    for (int kt = 0; kt < 16; ++kt)
      Wf[q][kt] = f2b8(Whh + (long)(q * 512 + j0 + lrow) * 512 + kt * 32 + lq * 8);

  float c[4] = {0.f, 0.f, 0.f, 0.f};
  // per-lane xg base: row b = b0+lq*4+r, col = q*512 + j0 + lrow
  const float* xgb = xg + (long)(b0 + lq * 4) * T * G4 + j0 + lrow;
  const ushort* hld = hbuf + (b0 + lrow) * H + lq * 8;  // h load base (A-frag)

  for (int t = 0; t < T; ++t) {
    // xg(t) loads: independent of the barrier -> issue first (plain, cached)
    float xgv[4][4];
#pragma unroll
    for (int q = 0; q < 4; ++q)
#pragma unroll
      for (int r = 0; r < 4; ++r)
        xgv[q][r] = xgb[((long)r * T + t) * G4 + q * 512];

    f32x4 acc[4] = {};
    if (t > 0) {
      if (tid == 0)
        while (__hip_atomic_load(&mycnt[t - 1], __ATOMIC_RELAXED, __HIP_MEMORY_SCOPE_AGENT) < NHALF)
          __builtin_amdgcn_s_sleep(1);
      __syncthreads();
      // coherent h(t-1) loads from slot t&1 (compiler-tracked atomic loads;
      // per-lane fragment = 16B at stride 64B -> 2 x ull per ktile)
      const unsigned long long* hp64 =
          (const unsigned long long*)(hld + (size_t)(t & 1) * (B * H));
      unsigned long long hw[32];
#pragma unroll
      for (int kt = 0; kt < 16; ++kt) {
        hw[2 * kt] = __hip_atomic_load(hp64 + kt * 8, __ATOMIC_RELAXED, __HIP_MEMORY_SCOPE_AGENT);
        hw[2 * kt + 1] = __hip_atomic_load(hp64 + kt * 8 + 1, __ATOMIC_RELAXED, __HIP_MEMORY_SCOPE_AGENT);
      }
#pragma unroll
      for (int kt = 0; kt < 16; ++kt) {
        const uint4 hv = make_uint4(
            (unsigned)hw[2 * kt], (unsigned)(hw[2 * kt] >> 32),
            (unsigned)hw[2 * kt + 1], (unsigned)(hw[2 * kt + 1] >> 32));
        const bf16x8 ah = __builtin_bit_cast(bf16x8, hv);
#pragma unroll
        for (int q = 0; q < 4; ++q)
          acc[q] = __builtin_amdgcn_mfma_f32_16x16x32_bf16(ah, Wf[q][kt], acc[q], 0, 0, 0);
      }
    }

    ushort* hn = hbuf + (size_t)((t + 1) & 1) * (B * H);
#pragma unroll
    for (int r = 0; r < 4; ++r) {
      const float iv = fast_sigmoid(acc[0][r] + xgv[0][r]);
      const float fv = fast_sigmoid(acc[1][r] + xgv[1][r]);
      const float gv = fast_tanh(acc[2][r] + xgv[2][r]);
      const float ov = fast_sigmoid(acc[3][r] + xgv[3][r]);
      c[r] = fv * c[r] + iv * gv;
      const float h = ov * fast_tanh(c[r]);
      const int b = b0 + lq * 4 + r, j = j0 + lrow;
      const ushort hb = f2b(h);
      st_coh_u16(hn + b * H + j, hb);
      if (seq_bf) seq_bf[((long)b * T + t) * H + j] = hb;      // plain store
      if (seq_f32) seq_f32[((long)b * T + t) * H + j] = h;     // plain store
    }
    wait_vm0();       // h stores retired to the agent-coherent point
    __syncthreads();  // all 4 waves of this WG done
    if (tid == 0)
      __hip_atomic_fetch_add(&mycnt[t], 1u, __ATOMIC_RELAXED, __HIP_MEMORY_SCOPE_AGENT);
  }
}

// ---------- launch ----------
extern "C" void kernel_launch(void* const* d_in, const int* in_sizes, int n_in,
                              void* d_out, int out_size, void* d_ws, size_t ws_size,
                              hipStream_t stream) {
  const float* feats = (const float*)d_in[0];
  const float* Wih0 = (const float*)d_in[1];
  const float* Whh0 = (const float*)d_in[2];
  const float* bih0 = (const float*)d_in[3];
  const float* bhh0 = (const float*)d_in[4];
  const float* Wih1 = (const float*)d_in[5];
  const float* Whh1 = (const float*)d_in[6];
  const float* bih1 = (const float*)d_in[7];
  const float* bhh1 = (const float*)d_in[8];

  // workspace layout (bytes):
  //   xg   : [0, 134217728)              16384*2048*4
  //   seq  : [134217728, 150994944)      16384*512*2
  //   hbuf : [150994944, 151060480)      2*32*512*2
  //   cnt  : [151060480, 151068672)      2 scans * 2 halves * 512 * 4
  char* ws = (char*)d_ws;
  float* xg      = (float*)(ws + 0);
  ushort* seq    = (ushort*)(ws + 134217728);
  ushort* hbuf   = (ushort*)(ws + 150994944);
  unsigned* cnt  = (unsigned*)(ws + 151060480);

  hipMemsetAsync(cnt, 0, 4 * T * sizeof(unsigned), stream);

  // layer 0 input GEMM: xg = feats * Wih0^T + (bih0 + bhh0)  [fp32-accurate]
  gemm3<0><<<dim3(M_ALL / 128, G4 / 128), dim3(256), 0, stream>>>(
      feats, nullptr, Wih0, bih0, bhh0, xg, M_ALL, G4, IN);

  // layer 0 scan -> seq (bf16)
  lstm_scan<<<dim3(NWG), dim3(256), 0, stream>>>(
      Whh0, xg, seq, nullptr, hbuf, cnt);

  // layer 1 input GEMM: xg = seq * Wih1^T + (bih1 + bhh1)
  gemm3<2><<<dim3(M_ALL / 128, G4 / 128), dim3(256), 0, stream>>>(
      nullptr, seq, Wih1, bih1, bhh1, xg, M_ALL, G4, H);

  // layer 1 scan -> d_out (fp32)
  lstm_scan<<<dim3(NWG), dim3(256), 0, stream>>>(
      Whh1, xg, nullptr, (float*)d_out, hbuf, cnt + 2 * T);
}

// Round 6
// 7628.094 us; speedup vs baseline: 1.7688x; 1.0377x over previous
//
#include <hip/hip_runtime.h>

typedef __bf16 bf16x8 __attribute__((ext_vector_type(8)));
typedef float f32x4 __attribute__((ext_vector_type(4)));

static constexpr int B = 32, T = 512, IN = 2048, H = 512;
static constexpr int G4 = 4 * H;      // 2048 gate columns
static constexpr int M_ALL = B * T;   // 16384
static constexpr int NWG = 16;        // scan workgroups (8 per batch-half)
static constexpr unsigned NHALF = 8;  // barrier arrivals per half

// ---------- helpers ----------
__device__ __forceinline__ ushort f2b(float f) {  // fp32 -> bf16 RNE
  unsigned u = __float_as_uint(f);
  u = (u + 0x7FFFu + ((u >> 16) & 1u)) >> 16;
  return (ushort)u;
}
__device__ __forceinline__ float b2f(ushort h) {
  return __uint_as_float(((unsigned)h) << 16);
}
__device__ __forceinline__ float fast_sigmoid(float x) {
  float e = __expf(-x);
  return 1.0f / (1.0f + e);
}
__device__ __forceinline__ float fast_tanh(float x) {
  float ax = fabsf(x);
  float e = __expf(-2.0f * ax);
  float t = (1.0f - e) / (1.0f + e);
  return copysignf(t, x);
}
// split 8 fp32 into bf16 hi + bf16 lo (residual), packed as uint4 each
__device__ __forceinline__ void split8(const float4 a, const float4 b, uint4& hi, uint4& lo) {
  float x[8] = {a.x, a.y, a.z, a.w, b.x, b.y, b.z, b.w};
  ushort h[8], l[8];
#pragma unroll
  for (int i = 0; i < 8; ++i) {
    h[i] = f2b(x[i]);
    l[i] = f2b(x[i] - b2f(h[i]));
  }
  hi = make_uint4(h[0] | ((unsigned)h[1] << 16), h[2] | ((unsigned)h[3] << 16),
                  h[4] | ((unsigned)h[5] << 16), h[6] | ((unsigned)h[7] << 16));
  lo = make_uint4(l[0] | ((unsigned)l[1] << 16), l[2] | ((unsigned)l[3] << 16),
                  l[4] | ((unsigned)l[5] << 16), l[6] | ((unsigned)l[7] << 16));
}
__device__ __forceinline__ bf16x8 f2b8(const float* p) {  // 8 fp32 -> bf16x8 (hi)
  float4 a = *(const float4*)p, b = *(const float4*)(p + 4);
  uint4 u;
  u.x = f2b(a.x) | ((unsigned)f2b(a.y) << 16);
  u.y = f2b(a.z) | ((unsigned)f2b(a.w) << 16);
  u.z = f2b(b.x) | ((unsigned)f2b(b.y) << 16);
  u.w = f2b(b.z) | ((unsigned)f2b(b.w) << 16);
  return __builtin_bit_cast(bf16x8, u);
}

// ---------- coherent (agent-scope) producer store ----------
__device__ __forceinline__ void st_coh_u16(void* p, ushort v) {
  unsigned vv = v;
  asm volatile("global_store_short %0, %1, off sc1" :: "v"(p), "v"(vv) : "memory");
}
__device__ __forceinline__ void wait_vm0() {
  asm volatile("s_waitcnt vmcnt(0)" ::: "memory");
}

// ---------- GEMM: C[M,N] = A[M,K]*Bm[N,K]^T + bias1[N]+bias2[N] ----------
// AMODE 0: A fp32, split hi/lo during staging (3-term, fp32-accurate).
// AMODE 2: A bf16 (2-term: aH*bH + aH*bL). B (weights) fp32, split on stage.
template <int AMODE>
__global__ __launch_bounds__(256) void gemm3(
    const float* __restrict__ Af, const ushort* __restrict__ Abf,
    const float* __restrict__ Bf,
    const float* __restrict__ bias1, const float* __restrict__ bias2,
    float* __restrict__ C, int M, int N, int K) {
  __shared__ ushort AsH[128][40], AsL[128][40], BsH[128][40], BsL[128][40];
  const int m0 = blockIdx.x * 128, n0 = blockIdx.y * 128;
  const int tid = threadIdx.x, lane = tid & 63, wave = tid >> 6;
  const int wm = (wave & 1) * 64, wn = (wave >> 1) * 64;
  const int lrow = lane & 15, lq = lane >> 4;
  const int sr = tid >> 2;        // staging row 0..63
  const int sk = (tid & 3) * 8;   // staging k offset (elements)

  f32x4 acc[4][4] = {};

  for (int k0 = 0; k0 < K; k0 += 32) {
    __syncthreads();
#pragma unroll
    for (int half = 0; half < 2; ++half) {
      const int r = sr + half * 64;
      if constexpr (AMODE == 0) {
        const float* p = Af + (long)(m0 + r) * K + k0 + sk;
        uint4 hi, lo;
        split8(*(const float4*)p, *(const float4*)(p + 4), hi, lo);
        *(uint4*)&AsH[r][sk] = hi;
        *(uint4*)&AsL[r][sk] = lo;
      } else {
        *(uint4*)&AsH[r][sk] = *(const uint4*)(Abf + (long)(m0 + r) * K + k0 + sk);
      }
      const float* q = Bf + (long)(n0 + r) * K + k0 + sk;
      uint4 bh, bl;
      split8(*(const float4*)q, *(const float4*)(q + 4), bh, bl);
      *(uint4*)&BsH[r][sk] = bh;
      *(uint4*)&BsL[r][sk] = bl;
    }
    __syncthreads();
    bf16x8 aH[4], aL[4], bH[4], bL[4];
#pragma unroll
    for (int i = 0; i < 4; ++i) {
      aH[i] = __builtin_bit_cast(bf16x8, *(const uint4*)&AsH[wm + i * 16 + lrow][lq * 8]);
      if constexpr (AMODE == 0)
        aL[i] = __builtin_bit_cast(bf16x8, *(const uint4*)&AsL[wm + i * 16 + lrow][lq * 8]);
      bH[i] = __builtin_bit_cast(bf16x8, *(const uint4*)&BsH[wn + i * 16 + lrow][lq * 8]);
      bL[i] = __builtin_bit_cast(bf16x8, *(const uint4*)&BsL[wn + i * 16 + lrow][lq * 8]);
    }
#pragma unroll
    for (int mt = 0; mt < 4; ++mt)
#pragma unroll
      for (int nt = 0; nt < 4; ++nt) {
        acc[mt][nt] = __builtin_amdgcn_mfma_f32_16x16x32_bf16(aH[mt], bH[nt], acc[mt][nt], 0, 0, 0);
        acc[mt][nt] = __builtin_amdgcn_mfma_f32_16x16x32_bf16(aH[mt], bL[nt], acc[mt][nt], 0, 0, 0);
        if constexpr (AMODE == 0)
          acc[mt][nt] = __builtin_amdgcn_mfma_f32_16x16x32_bf16(aL[mt], bH[nt], acc[mt][nt], 0, 0, 0);
      }
  }

#pragma unroll
  for (int mt = 0; mt < 4; ++mt)
#pragma unroll
    for (int nt = 0; nt < 4; ++nt) {
      const int col = n0 + wn + nt * 16 + lrow;
      const float bsum = bias1[col] + bias2[col];
#pragma unroll
      for (int r = 0; r < 4; ++r) {
        const int row = m0 + wm + mt * 16 + lq * 4 + r;
        C[(long)row * N + col] = acc[mt][nt][r] + bsum;
      }
    }
}

// ---------- recurrent scan (K-split) ----------
// 16 WGs x 512 thr (8 waves). blockIdx>>3 = batch half; within WG, wave pair
// (jl = wave>>1) owns j-tile ((blockIdx&7)*4+jl)*16, with ksel = wave&1
// splitting K=512 into two halves -> Wf[4][8] = 128 VGPR/wave, so W_hh STAYS
// IN REGISTERS (round 5's 256-VGPR Wf was rematerialized every step: 176
// VGPR_Count + 14% VALUBusy on active CUs = ~3600 cyc/step of reload+convert).
// Partial accs summed via LDS; even-K wave does gates + coherent h store.
__global__ __launch_bounds__(512, 2) void lstm_scan(
    const float* __restrict__ Whh,    // [2048][512] fp32
    const float* __restrict__ xg,     // [B*T][2048] fp32, row m=b*T+t
    ushort* __restrict__ seq_bf,      // [B*T][512] bf16 (layer0) or null
    float* __restrict__ seq_f32,      // [B*T][512] fp32 (layer1) or null
    ushort* __restrict__ hbuf,        // [2 slots][B][H] ushort, coherent
    unsigned* __restrict__ cnt) {     // [2][T] zeroed counters (per half)
  const int tid = threadIdx.x, lane = tid & 63;
  const int wave = tid >> 6;          // 0..7
  const int jl = wave >> 1;           // j-tile slot in WG, 0..3
  const int ksel = wave & 1;          // K half
  const int half = blockIdx.x >> 3;
  const int j0 = ((blockIdx.x & 7) * 4 + jl) * 16;
  const int b0 = half * 16;
  const int lrow = lane & 15, lq = lane >> 4;
  unsigned* mycnt = cnt + half * T;

  // W_hh K-slice -> registers (bf16 hi). 4 gates x 8 ktiles x 4 VGPR = 128.
  bf16x8 Wf[4][8];
#pragma unroll
  for (int q = 0; q < 4; ++q)
#pragma unroll
    for (int k = 0; k < 8; ++k)
      Wf[q][k] = f2b8(Whh + (long)(q * 512 + j0 + lrow) * 512 + (ksel * 8 + k) * 32 + lq * 8);

  __shared__ float4 red[4][4][64];    // partial-acc exchange, 16 KB

  float c[4] = {0.f, 0.f, 0.f, 0.f};
  const float* xgb = xg + (long)(b0 + lq * 4) * T * G4 + j0 + lrow;
  const ushort* hld = hbuf + (b0 + lrow) * H + lq * 8;  // A-frag base

  for (int t = 0; t < T; ++t) {
    // xg(t): only the finalizing (even-K) wave needs it; plain cached loads
    float xgv[4][4];
    if (ksel == 0) {
#pragma unroll
      for (int q = 0; q < 4; ++q)
#pragma unroll
        for (int r = 0; r < 4; ++r)
          xgv[q][r] = xgb[((long)r * T + t) * G4 + q * 512];
    }

    if (t > 0) {
      if (tid == 0)
        while (__hip_atomic_load(&mycnt[t - 1], __ATOMIC_RELAXED, __HIP_MEMORY_SCOPE_AGENT) < NHALF)
          __builtin_amdgcn_s_sleep(1);
      __syncthreads();
    }

    f32x4 acc[4] = {};
    if (t > 0) {
      // coherent h(t-1) K-slice loads (compiler-tracked atomic loads)
      const unsigned long long* hp64 =
          (const unsigned long long*)(hld + (size_t)(t & 1) * (B * H));
      unsigned long long hw[16];
#pragma unroll
      for (int k = 0; k < 8; ++k) {
        const int kt = ksel * 8 + k;
        hw[2 * k] = __hip_atomic_load(hp64 + kt * 8, __ATOMIC_RELAXED, __HIP_MEMORY_SCOPE_AGENT);
        hw[2 * k + 1] = __hip_atomic_load(hp64 + kt * 8 + 1, __ATOMIC_RELAXED, __HIP_MEMORY_SCOPE_AGENT);
      }
#pragma unroll
      for (int k = 0; k < 8; ++k) {
        const uint4 hv = make_uint4(
            (unsigned)hw[2 * k], (unsigned)(hw[2 * k] >> 32),
            (unsigned)hw[2 * k + 1], (unsigned)(hw[2 * k + 1] >> 32));
        const bf16x8 ah = __builtin_bit_cast(bf16x8, hv);
#pragma unroll
        for (int q = 0; q < 4; ++q)
          acc[q] = __builtin_amdgcn_mfma_f32_16x16x32_bf16(ah, Wf[q][k], acc[q], 0, 0, 0);
      }
    }

    // K-reduction: odd-K wave -> LDS, even-K wave sums
    if (ksel == 1) {
#pragma unroll
      for (int i = 0; i < 4; ++i)
        red[jl][i][lane] = __builtin_bit_cast(float4, acc[i]);
    }
    __syncthreads();
    if (ksel == 0) {
#pragma unroll
      for (int i = 0; i < 4; ++i) {
        const float4 p = red[jl][i][lane];
        acc[i][0] += p.x; acc[i][1] += p.y; acc[i][2] += p.z; acc[i][3] += p.w;
      }
      ushort* hn = hbuf + (size_t)((t + 1) & 1) * (B * H);
#pragma unroll
      for (int r = 0; r < 4; ++r) {
        const float iv = fast_sigmoid(acc[0][r] + xgv[0][r]);
        const float fv = fast_sigmoid(acc[1][r] + xgv[1][r]);
        const float gv = fast_tanh(acc[2][r] + xgv[2][r]);
        const float ov = fast_sigmoid(acc[3][r] + xgv[3][r]);
        c[r] = fv * c[r] + iv * gv;
        const float h = ov * fast_tanh(c[r]);
        const int b = b0 + lq * 4 + r, j = j0 + lrow;
        const ushort hb = f2b(h);
        st_coh_u16(hn + b * H + j, hb);
        if (seq_bf) seq_bf[((long)b * T + t) * H + j] = hb;
        if (seq_f32) seq_f32[((long)b * T + t) * H + j] = h;
      }
      wait_vm0();     // h stores retired to the agent-coherent point
    }
    __syncthreads();  // all 8 waves aligned; producers' stores are done
    if (tid == 0)
      __hip_atomic_fetch_add(&mycnt[t], 1u, __ATOMIC_RELAXED, __HIP_MEMORY_SCOPE_AGENT);
  }
}

// ---------- launch ----------
extern "C" void kernel_launch(void* const* d_in, const int* in_sizes, int n_in,
                              void* d_out, int out_size, void* d_ws, size_t ws_size,
                              hipStream_t stream) {
  const float* feats = (const float*)d_in[0];
  const float* Wih0 = (const float*)d_in[1];
  const float* Whh0 = (const float*)d_in[2];
  const float* bih0 = (const float*)d_in[3];
  const float* bhh0 = (const float*)d_in[4];
  const float* Wih1 = (const float*)d_in[5];
  const float* Whh1 = (const float*)d_in[6];
  const float* bih1 = (const float*)d_in[7];
  const float* bhh1 = (const float*)d_in[8];

  // workspace layout (bytes):
  //   xg   : [0, 134217728)              16384*2048*4
  //   seq  : [134217728, 150994944)      16384*512*2
  //   hbuf : [150994944, 151060480)      2*32*512*2
  //   cnt  : [151060480, 151068672)      2 scans * 2 halves * 512 * 4
  char* ws = (char*)d_ws;
  float* xg      = (float*)(ws + 0);
  ushort* seq    = (ushort*)(ws + 134217728);
  ushort* hbuf   = (ushort*)(ws + 150994944);
  unsigned* cnt  = (unsigned*)(ws + 151060480);

  hipMemsetAsync(cnt, 0, 4 * T * sizeof(unsigned), stream);

  // layer 0 input GEMM: xg = feats * Wih0^T + (bih0 + bhh0)  [fp32-accurate]
  gemm3<0><<<dim3(M_ALL / 128, G4 / 128), dim3(256), 0, stream>>>(
      feats, nullptr, Wih0, bih0, bhh0, xg, M_ALL, G4, IN);

  // layer 0 scan -> seq (bf16)
  lstm_scan<<<dim3(NWG), dim3(512), 0, stream>>>(
      Whh0, xg, seq, nullptr, hbuf, cnt);

  // layer 1 input GEMM: xg = seq * Wih1^T + (bih1 + bhh1)
  gemm3<2><<<dim3(M_ALL / 128, G4 / 128), dim3(256), 0, stream>>>(
      nullptr, seq, Wih1, bih1, bhh1, xg, M_ALL, G4, H);

  // layer 1 scan -> d_out (fp32)
  lstm_scan<<<dim3(NWG), dim3(512), 0, stream>>>(
      Whh1, xg, nullptr, (float*)d_out, hbuf, cnt + 2 * T);
}